// Round 11
// baseline (58.438 us; speedup 1.0000x reference)
//
#include <hip/hip_runtime.h>

// SpatialTransformer: batched affine warp + trilinear resample.
// vol: [4,160,160,160,2] fp32, trf: [4,3,4] fp32 -> out: [4,160,160,160,2] fp32.
//
// r3: z-corner pairing 8->4 gathers/voxel (98.5 -> 73.8 us).
// r6: scalar b + s_load matrix (73.8 -> 59.4).
// r8: 3D tile 8j x 32k x TI + pipeline (59.4 -> 52.3). r9: depth-2/TI=8 ~flat
//     (51.7) -> not MLP-starved.
// r10: INVALID - static dummy LDS was dead-store-eliminated (LDS_Block_Size=0,
//      occupancy unchanged). Hypothesis untested.
// r11: r9 kernel + 56KB DYNAMIC shared mem at launch (cannot be elided) ->
//      exactly 2 blocks/CU, combined L1 working set ~36KB ~ L1 capacity.
//      Discriminates L1-thrash vs gather-pipe floor.

constexpr int D = 160, H = 160, W = 160, C = 2;
constexpr unsigned VOX_PER_B = D * H * W;            // 4,096,000
constexpr int TI = 8, TJ = 8, TK = 32;
constexpr unsigned NTI = D / TI;                     // 20
constexpr unsigned NTJ = H / TJ;                     // 20
constexpr unsigned NTK = W / TK;                     // 5
constexpr unsigned TPV = NTI * NTJ * NTK;            // 2,000 tiles per volume
constexpr unsigned NBLOCKS = 4u * TPV;               // 8,000
constexpr unsigned NXCD = 8;
constexpr unsigned CHUNK = NBLOCKS / NXCD;           // 1,000
constexpr unsigned DYN_LDS = 56u * 1024u;            // -> 2 blocks/CU cap

struct VPair { float2 lo, hi; };   // 16B: voxels [zb] and [zb+1] of one row

struct Gset { int p00, p01, p10, p11; float wxl, wyl, wzl; };

// corner addresses + weights for one sample (reference clip semantics).
__device__ __forceinline__ Gset mkset(float lx, float ly, float lz)
{
    const float mx = 159.0f;
    lx = fminf(fmaxf(lx, 0.0f), mx);
    ly = fminf(fmaxf(ly, 0.0f), mx);
    lz = fminf(fmaxf(lz, 0.0f), mx);

    float fx0 = floorf(lx), fy0 = floorf(ly), fz0 = floorf(lz);
    float fx1 = fminf(fx0 + 1.0f, mx);
    float fy1 = fminf(fy0 + 1.0f, mx);
    float fz1 = fminf(fz0 + 1.0f, mx);

    int ix0 = (int)fx0, iy0 = (int)fy0, iz0 = (int)fz0;
    int ix1 = (int)fx1, iy1 = (int)fy1;

    Gset g;
    // voxelmorph convention: w_lo = loc1 - loc (weight of LOWER corner)
    g.wxl = fx1 - lx; g.wyl = fy1 - ly; g.wzl = fz1 - lz;

    // z-pair base: iz1 == zb+1 always. Clamp case (iz0==159 -> zb=158) has
    // lower-corner weight EXACTLY 0, so q.lo contributes nothing. No select.
    int zb = min(iz0, W - 2);
    int r0 = ix0 * H, r1 = ix1 * H;
    g.p00 = (r0 + iy0) * W + zb;
    g.p01 = (r0 + iy1) * W + zb;
    g.p10 = (r1 + iy0) * W + zb;
    g.p11 = (r1 + iy1) * W + zb;
    return g;
}

// factorized trilinear z -> y -> x (exact: high weights are 1 - low).
__device__ __forceinline__ float2 interp(VPair q00, VPair q01, VPair q10, VPair q11,
                                         const Gset& g)
{
    float wzl = g.wzl, wzh = 1.0f - wzl;
    float wyl = g.wyl, wyh = 1.0f - wyl;
    float wxl = g.wxl, wxh = 1.0f - wxl;

    float zx00 = q00.lo.x * wzl + q00.hi.x * wzh, zy00 = q00.lo.y * wzl + q00.hi.y * wzh;
    float zx01 = q01.lo.x * wzl + q01.hi.x * wzh, zy01 = q01.lo.y * wzl + q01.hi.y * wzh;
    float zx10 = q10.lo.x * wzl + q10.hi.x * wzh, zy10 = q10.lo.y * wzl + q10.hi.y * wzh;
    float zx11 = q11.lo.x * wzl + q11.hi.x * wzh, zy11 = q11.lo.y * wzl + q11.hi.y * wzh;

    float yx0 = zx00 * wyl + zx01 * wyh, yy0 = zy00 * wyl + zy01 * wyh;
    float yx1 = zx10 * wyl + zx11 * wyh, yy1 = zy10 * wyl + zy11 * wyh;

    float2 o;
    o.x = yx0 * wxl + yx1 * wxh;
    o.y = yy0 * wxl + yy1 * wxh;
    return o;
}

__global__ __launch_bounds__(256) void st_affine_trilinear(
    const float* __restrict__ vol,
    const float* __restrict__ trf,
    float* __restrict__ out)
{
    // dynamic LDS (size from dispatch) — occupancy limiter that survives DCE.
    extern __shared__ float lds_dyn[];

    // bijective chunked XCD swizzle; neighboring tiles share one XCD's L2.
    unsigned bid = blockIdx.x;
    unsigned swz = (bid & (NXCD - 1)) * CHUNK + (bid >> 3);

    // all block-uniform (scalar) decomposition:
    unsigned b  = swz / TPV;
    unsigned r  = swz - b * TPV;
    unsigned it = r / (NTJ * NTK);
    unsigned r2 = r - it * (NTJ * NTK);
    unsigned jt = r2 / NTK;
    unsigned kt = r2 - jt * NTK;
    unsigned i0 = it * TI, j0 = jt * TJ, k0 = kt * TK;

    // thread -> (j,k) within tile; lanes walk k (32-contiguous), wave = 2 rows.
    unsigned jl = threadIdx.x >> 5, kl = threadIdx.x & 31u;
    unsigned j = j0 + jl, k = k0 + kl;

    // affine row-major [3][4]; b uniform -> scalar s_loads.
    const float* m = trf + b * 12u;
    float m00 = m[0], m01 = m[1], m02 = m[2],  m03 = m[3];
    float m10 = m[4], m11 = m[5], m12 = m[6],  m13 = m[7];
    float m20 = m[8], m21 = m[9], m22 = m[10], m23 = m[11];

    // data-dependent (never-true) touch so the extern array has a use.
    if (m00 > 1.0e30f) lds_dyn[threadIdx.x] = m00;

    const float cc = 79.5f;
    float xc = (float)i0 - cc, yc = (float)j - cc, zc = (float)k - cc;

    float lx = fmaf(m00, xc, fmaf(m01, yc, fmaf(m02, zc, m03 + cc)));
    float ly = fmaf(m10, xc, fmaf(m11, yc, fmaf(m12, zc, m13 + cc)));
    float lz = fmaf(m20, xc, fmaf(m21, yc, fmaf(m22, zc, m23 + cc)));

    const float2* vb = (const float2*)(vol) + (size_t)b * VOX_PER_B;
    unsigned o_idx = ((b * D + i0) * H + j) * W + k;   // float2 index

    // depth-2 software pipeline over TI=8 i-planes (12 loads in flight).
    Gset gA = mkset(lx, ly, lz);
    VPair a00 = *(const VPair*)(vb + gA.p00);
    VPair a01 = *(const VPair*)(vb + gA.p01);
    VPair a10 = *(const VPair*)(vb + gA.p10);
    VPair a11 = *(const VPair*)(vb + gA.p11);

    lx += m00; ly += m10; lz += m20;          // plane 1 coords (x-col of M)
    Gset gB = mkset(lx, ly, lz);
    VPair b00 = *(const VPair*)(vb + gB.p00);
    VPair b01 = *(const VPair*)(vb + gB.p01);
    VPair b10 = *(const VPair*)(vb + gB.p10);
    VPair b11 = *(const VPair*)(vb + gB.p11);

    #pragma unroll
    for (int t = 0; t < TI; ++t) {
        // issue plane t+2's gathers FIRST (keeps depth-2 in flight)
        Gset gN;
        VPair n00, n01, n10, n11;
        if (t + 2 < TI) {
            lx += m00; ly += m10; lz += m20;
            gN = mkset(lx, ly, lz);
            n00 = *(const VPair*)(vb + gN.p00);
            n01 = *(const VPair*)(vb + gN.p01);
            n10 = *(const VPair*)(vb + gN.p10);
            n11 = *(const VPair*)(vb + gN.p11);
        }

        // consume plane t (buffer A)
        float2 o = interp(a00, a01, a10, a11, gA);
        double od;
        __builtin_memcpy(&od, &o, 8);
        __builtin_nontemporal_store(od, (double*)out + o_idx + (unsigned)t * (H * W));

        // shift buffers: A <- B, B <- N (SSA renames after unroll)
        gA = gB; a00 = b00; a01 = b01; a10 = b10; a11 = b11;
        gB = gN; b00 = n00; b01 = n01; b10 = n10; b11 = n11;
    }
}

extern "C" void kernel_launch(void* const* d_in, const int* in_sizes, int n_in,
                              void* d_out, int out_size, void* d_ws, size_t ws_size,
                              hipStream_t stream) {
    const float* vol = (const float*)d_in[0];
    const float* trf = (const float*)d_in[1];
    float* out = (float*)d_out;

    st_affine_trilinear<<<NBLOCKS, 256, DYN_LDS, stream>>>(vol, trf, out);
}

// Round 12
// 51.402 us; speedup vs baseline: 1.1369x; 1.1369x over previous
//
#include <hip/hip_runtime.h>

// SpatialTransformer: batched affine warp + trilinear resample.
// vol: [4,160,160,160,2] fp32, trf: [4,3,4] fp32 -> out: [4,160,160,160,2] fp32.
//
// Final structure (best = r9, 51.7 us):
//   - XCD chunked bijective swizzle (FETCH 252.7 -> 48.9 MB)
//   - z-corner pairing: 4 x dwordx4 gathers/voxel (structural minimum)
//   - scalar b / s_load matrix, block-uniform tile decompose
//   - 3D tile 8j x 32k x TI=8, depth-2 i-plane software pipeline
//   - NT streaming stores
// r10/r11 established: NOT L1-capacity-bound (residency cap hurt: 58.4 us),
// NOT MLP-starved (depth-2 flat). VMEM pipe throughput-bound at ~15 cyc per
// 64-lane gather instruction.
// r12: revert r11's LDS limiter; corner addresses via 0/1-select deltas
// (saves 2 cvt + 3 mul per sample).

constexpr int D = 160, H = 160, W = 160, C = 2;
constexpr unsigned VOX_PER_B = D * H * W;            // 4,096,000
constexpr int TI = 8, TJ = 8, TK = 32;
constexpr unsigned NTI = D / TI;                     // 20
constexpr unsigned NTJ = H / TJ;                     // 20
constexpr unsigned NTK = W / TK;                     // 5
constexpr unsigned TPV = NTI * NTJ * NTK;            // 2,000 tiles per volume
constexpr unsigned NBLOCKS = 4u * TPV;               // 8,000
constexpr unsigned NXCD = 8;
constexpr unsigned CHUNK = NBLOCKS / NXCD;           // 1,000

struct VPair { float2 lo, hi; };   // 16B: voxels [zb] and [zb+1] of one row

struct Gset { int p00, p01, p10, p11; float wxl, wyl, wzl; };

// corner addresses + weights for one sample (reference clip semantics).
__device__ __forceinline__ Gset mkset(float lx, float ly, float lz)
{
    const float mx = 159.0f;
    lx = fminf(fmaxf(lx, 0.0f), mx);
    ly = fminf(fmaxf(ly, 0.0f), mx);
    lz = fminf(fmaxf(lz, 0.0f), mx);

    float fx0 = floorf(lx), fy0 = floorf(ly), fz0 = floorf(lz);
    float fx1 = fminf(fx0 + 1.0f, mx);
    float fy1 = fminf(fy0 + 1.0f, mx);
    float fz1 = fminf(fz0 + 1.0f, mx);

    int ix0 = (int)fx0, iy0 = (int)fy0, iz0 = (int)fz0;

    Gset g;
    // voxelmorph convention: w_lo = loc1 - loc (weight of LOWER corner)
    g.wxl = fx1 - lx; g.wyl = fy1 - ly; g.wzl = fz1 - lz;

    // z-pair base: iz1 == zb+1 always. Clamp case (iz0==159 -> zb=158) has
    // lower-corner weight EXACTLY 0, so q.lo contributes nothing. No select.
    int zb = min(iz0, W - 2);

    // upper-corner deltas are 0 or 1 plane/row: select, no extra cvt/mul.
    int dxHW = (fx1 > fx0) ? H * W : 0;
    int dyW  = (fy1 > fy0) ? W : 0;

    g.p00 = (ix0 * H + iy0) * W + zb;
    g.p01 = g.p00 + dyW;
    g.p10 = g.p00 + dxHW;
    g.p11 = g.p10 + dyW;
    return g;
}

// factorized trilinear z -> y -> x (exact: high weights are 1 - low).
__device__ __forceinline__ float2 interp(VPair q00, VPair q01, VPair q10, VPair q11,
                                         const Gset& g)
{
    float wzl = g.wzl, wzh = 1.0f - wzl;
    float wyl = g.wyl, wyh = 1.0f - wyl;
    float wxl = g.wxl, wxh = 1.0f - wxl;

    float zx00 = q00.lo.x * wzl + q00.hi.x * wzh, zy00 = q00.lo.y * wzl + q00.hi.y * wzh;
    float zx01 = q01.lo.x * wzl + q01.hi.x * wzh, zy01 = q01.lo.y * wzl + q01.hi.y * wzh;
    float zx10 = q10.lo.x * wzl + q10.hi.x * wzh, zy10 = q10.lo.y * wzl + q10.hi.y * wzh;
    float zx11 = q11.lo.x * wzl + q11.hi.x * wzh, zy11 = q11.lo.y * wzl + q11.hi.y * wzh;

    float yx0 = zx00 * wyl + zx01 * wyh, yy0 = zy00 * wyl + zy01 * wyh;
    float yx1 = zx10 * wyl + zx11 * wyh, yy1 = zy10 * wyl + zy11 * wyh;

    float2 o;
    o.x = yx0 * wxl + yx1 * wxh;
    o.y = yy0 * wxl + yy1 * wxh;
    return o;
}

__global__ __launch_bounds__(256) void st_affine_trilinear(
    const float* __restrict__ vol,
    const float* __restrict__ trf,
    float* __restrict__ out)
{
    // bijective chunked XCD swizzle; neighboring tiles share one XCD's L2.
    unsigned bid = blockIdx.x;
    unsigned swz = (bid & (NXCD - 1)) * CHUNK + (bid >> 3);

    // all block-uniform (scalar) decomposition:
    unsigned b  = swz / TPV;
    unsigned r  = swz - b * TPV;
    unsigned it = r / (NTJ * NTK);
    unsigned r2 = r - it * (NTJ * NTK);
    unsigned jt = r2 / NTK;
    unsigned kt = r2 - jt * NTK;
    unsigned i0 = it * TI, j0 = jt * TJ, k0 = kt * TK;

    // thread -> (j,k) within tile; lanes walk k (32-contiguous), wave = 2 rows.
    unsigned jl = threadIdx.x >> 5, kl = threadIdx.x & 31u;
    unsigned j = j0 + jl, k = k0 + kl;

    // affine row-major [3][4]; b uniform -> scalar s_loads.
    const float* m = trf + b * 12u;
    float m00 = m[0], m01 = m[1], m02 = m[2],  m03 = m[3];
    float m10 = m[4], m11 = m[5], m12 = m[6],  m13 = m[7];
    float m20 = m[8], m21 = m[9], m22 = m[10], m23 = m[11];

    const float cc = 79.5f;
    float xc = (float)i0 - cc, yc = (float)j - cc, zc = (float)k - cc;

    float lx = fmaf(m00, xc, fmaf(m01, yc, fmaf(m02, zc, m03 + cc)));
    float ly = fmaf(m10, xc, fmaf(m11, yc, fmaf(m12, zc, m13 + cc)));
    float lz = fmaf(m20, xc, fmaf(m21, yc, fmaf(m22, zc, m23 + cc)));

    const float2* vb = (const float2*)(vol) + (size_t)b * VOX_PER_B;
    unsigned o_idx = ((b * D + i0) * H + j) * W + k;   // float2 index

    // depth-2 software pipeline over TI=8 i-planes (12 loads in flight).
    Gset gA = mkset(lx, ly, lz);
    VPair a00 = *(const VPair*)(vb + gA.p00);
    VPair a01 = *(const VPair*)(vb + gA.p01);
    VPair a10 = *(const VPair*)(vb + gA.p10);
    VPair a11 = *(const VPair*)(vb + gA.p11);

    lx += m00; ly += m10; lz += m20;          // plane 1 coords (x-col of M)
    Gset gB = mkset(lx, ly, lz);
    VPair b00 = *(const VPair*)(vb + gB.p00);
    VPair b01 = *(const VPair*)(vb + gB.p01);
    VPair b10 = *(const VPair*)(vb + gB.p10);
    VPair b11 = *(const VPair*)(vb + gB.p11);

    #pragma unroll
    for (int t = 0; t < TI; ++t) {
        // issue plane t+2's gathers FIRST (keeps depth-2 in flight)
        Gset gN;
        VPair n00, n01, n10, n11;
        if (t + 2 < TI) {
            lx += m00; ly += m10; lz += m20;
            gN = mkset(lx, ly, lz);
            n00 = *(const VPair*)(vb + gN.p00);
            n01 = *(const VPair*)(vb + gN.p01);
            n10 = *(const VPair*)(vb + gN.p10);
            n11 = *(const VPair*)(vb + gN.p11);
        }

        // consume plane t (buffer A)
        float2 o = interp(a00, a01, a10, a11, gA);
        double od;
        __builtin_memcpy(&od, &o, 8);
        __builtin_nontemporal_store(od, (double*)out + o_idx + (unsigned)t * (H * W));

        // shift buffers: A <- B, B <- N (SSA renames after unroll)
        gA = gB; a00 = b00; a01 = b01; a10 = b10; a11 = b11;
        gB = gN; b00 = n00; b01 = n01; b10 = n10; b11 = n11;
    }
}

extern "C" void kernel_launch(void* const* d_in, const int* in_sizes, int n_in,
                              void* d_out, int out_size, void* d_ws, size_t ws_size,
                              hipStream_t stream) {
    const float* vol = (const float*)d_in[0];
    const float* trf = (const float*)d_in[1];
    float* out = (float*)d_out;

    st_affine_trilinear<<<NBLOCKS, 256, 0, stream>>>(vol, trf, out);
}